// Round 1
// baseline (85.001 us; speedup 1.0000x reference)
//
#include <hip/hip_runtime.h>
#include <math.h>

#define N_POINTS 8192
#define N_PAIRS  262144

// ---------------- Kernel A: partition function ----------------
// part_raw = sum_{i,j} 1/(1 + ||xi-xj||^2)  (diagonal included, == N exactly)
constexpr int A_BLOCKS  = 512;
constexpr int A_THREADS = 256;
constexpr int A_ROWS    = N_POINTS / A_BLOCKS;   // 16 rows per block
constexpr int A_TPR     = A_THREADS / A_ROWS;    // 16 threads per row

__global__ __launch_bounds__(A_THREADS)
void part_kernel(const float* __restrict__ logits, float* __restrict__ partials) {
    __shared__ float2 pts[N_POINTS];             // 64 KiB
    __shared__ float wsum[A_THREADS / 64];

    const int t = threadIdx.x;

    // cooperative stage: 8192 float2 == 4096 float4, coalesced
    const float4* src = (const float4*)logits;
    float4* dst = (float4*)pts;
    for (int k = t; k < N_POINTS / 2; k += A_THREADS) dst[k] = src[k];
    __syncthreads();

    const int row = blockIdx.x * A_ROWS + (t / A_TPR);
    const int c0  = t % A_TPR;
    const float px = pts[row].x;
    const float py = pts[row].y;

    float acc = 0.0f;
    #pragma unroll 8
    for (int k = c0; k < N_POINTS; k += A_TPR) {
        const float dx = px - pts[k].x;
        const float dy = py - pts[k].y;
        const float d2 = __builtin_fmaf(dx, dx, __builtin_fmaf(dy, dy, 1.0f));
        acc += __builtin_amdgcn_rcpf(d2);        // v_rcp_f32, rel err ~2^-22
    }

    #pragma unroll
    for (int off = 32; off > 0; off >>= 1) acc += __shfl_down(acc, off, 64);
    const int w = t >> 6, l = t & 63;
    if (l == 0) wsum[w] = acc;
    __syncthreads();
    if (t == 0) {
        float s = 0.0f;
        #pragma unroll
        for (int i = 0; i < A_THREADS / 64; ++i) s += wsum[i];
        partials[blockIdx.x] = s;
    }
}

// ---------------- Kernel B: edge terms ----------------
// s1 = sum_e pij * (log(pij) + log(2 + ||xi-xj||^2)),  sp = sum_e pij
constexpr int B_BLOCKS  = 256;
constexpr int B_THREADS = 256;

__global__ __launch_bounds__(B_THREADS)
void edge_kernel(const float* __restrict__ pij,
                 const int* __restrict__ ei,
                 const int* __restrict__ ej,
                 const float* __restrict__ logits,
                 float* __restrict__ s1_partials,
                 float* __restrict__ sp_partials) {
    __shared__ float w1[B_THREADS / 64];
    __shared__ float w2[B_THREADS / 64];

    const int t = threadIdx.x;
    float s1 = 0.0f, sp = 0.0f;
    for (int e = blockIdx.x * B_THREADS + t; e < N_PAIRS; e += B_BLOCKS * B_THREADS) {
        const int a = ei[e];
        const int b = ej[e];
        const float ax = logits[2 * a],     ay = logits[2 * a + 1];
        const float bx = logits[2 * b],     by = logits[2 * b + 1];
        const float dx = ax - bx, dy = ay - by;
        const float d2 = __builtin_fmaf(dx, dx, __builtin_fmaf(dy, dy, 2.0f));
        const float p  = pij[e];
        s1 += p * (logf(p) + logf(d2));
        sp += p;
    }

    #pragma unroll
    for (int off = 32; off > 0; off >>= 1) {
        s1 += __shfl_down(s1, off, 64);
        sp += __shfl_down(sp, off, 64);
    }
    const int w = t >> 6, l = t & 63;
    if (l == 0) { w1[w] = s1; w2[w] = sp; }
    __syncthreads();
    if (t == 0) {
        float a1 = 0.0f, a2 = 0.0f;
        #pragma unroll
        for (int i = 0; i < B_THREADS / 64; ++i) { a1 += w1[i]; a2 += w2[i]; }
        s1_partials[blockIdx.x] = a1;
        sp_partials[blockIdx.x] = a2;
    }
}

// ---------------- Kernel C: final reduce + combine ----------------
__global__ __launch_bounds__(256)
void final_kernel(const float* __restrict__ partA,   // A_BLOCKS
                  const float* __restrict__ partS1,  // B_BLOCKS
                  const float* __restrict__ partSp,  // B_BLOCKS
                  float* __restrict__ out) {
    __shared__ double ra[4], rs[4], rp[4];
    const int t = threadIdx.x;

    double a = 0.0, s = 0.0, p = 0.0;
    for (int k = t; k < A_BLOCKS; k += 256) a += (double)partA[k];
    if (t < B_BLOCKS) { s = (double)partS1[t]; p = (double)partSp[t]; }

    #pragma unroll
    for (int off = 32; off > 0; off >>= 1) {
        a += __shfl_down(a, off, 64);
        s += __shfl_down(s, off, 64);
        p += __shfl_down(p, off, 64);
    }
    const int w = t >> 6, l = t & 63;
    if (l == 0) { ra[w] = a; rs[w] = s; rp[w] = p; }
    __syncthreads();
    if (t == 0) {
        double A = 0.0, S = 0.0, P = 0.0;
        #pragma unroll
        for (int i = 0; i < 4; ++i) { A += ra[i]; S += rs[i]; P += rp[i]; }
        A -= (double)N_POINTS;                 // remove diagonal
        out[0] = (float)(S + log(A) * P);
    }
}

extern "C" void kernel_launch(void* const* d_in, const int* in_sizes, int n_in,
                              void* d_out, int out_size, void* d_ws, size_t ws_size,
                              hipStream_t stream) {
    const float* pij    = (const float*)d_in[0];
    const int*   ei     = (const int*)d_in[1];
    const int*   ej     = (const int*)d_in[2];
    const float* logits = (const float*)d_in[3];
    float* out = (float*)d_out;

    float* ws     = (float*)d_ws;
    float* partA  = ws;                 // A_BLOCKS floats
    float* partS1 = ws + A_BLOCKS;      // B_BLOCKS floats
    float* partSp = ws + A_BLOCKS + B_BLOCKS;

    part_kernel<<<A_BLOCKS, A_THREADS, 0, stream>>>(logits, partA);
    edge_kernel<<<B_BLOCKS, B_THREADS, 0, stream>>>(pij, ei, ej, logits, partS1, partSp);
    final_kernel<<<1, 256, 0, stream>>>(partA, partS1, partSp, out);
}

// Round 2
// 81.487 us; speedup vs baseline: 1.0431x; 1.0431x over previous
//
#include <hip/hip_runtime.h>
#include <math.h>

#define N_POINTS 8192
#define N_PAIRS  262144

constexpr int BLOCKS  = 512;
constexpr int THREADS = 256;
constexpr int ROWS    = N_POINTS / BLOCKS;   // 16 partition rows per block
constexpr int TPR     = THREADS / ROWS;      // 16 threads per row
constexpr int EPB     = N_PAIRS / BLOCKS;    // 512 edges per block

// ---------------- Fused kernel: partition rows + edge terms ----------------
// partials[0*BLOCKS+b] = sum over block's rows of sum_k 1/(1+||xi-xk||^2)
// partials[1*BLOCKS+b] = sum over block's edges of pij*(log pij + log(2+d2))
// partials[2*BLOCKS+b] = sum over block's edges of pij
__global__ __launch_bounds__(THREADS)
void fused_kernel(const float* __restrict__ logits,
                  const float* __restrict__ pij,
                  const int* __restrict__ ei,
                  const int* __restrict__ ej,
                  float* __restrict__ partials) {
    __shared__ float2 pts[N_POINTS];             // 64 KiB -> 2 blocks/CU
    __shared__ float wred[3][THREADS / 64];

    const int t = threadIdx.x;
    const int b = blockIdx.x;

    // cooperative stage: 8192 float2 == 4096 float4, coalesced (L2/L3 hot: 64 KB src)
    {
        const float4* src = (const float4*)logits;
        float4* dst = (float4*)pts;
        #pragma unroll
        for (int k = t; k < N_POINTS / 2; k += THREADS) dst[k] = src[k];
    }
    __syncthreads();

    // ---- phase 1: partition function rows (broadcast-friendly LDS pattern:
    //      lanes 0..15 hit 16 distinct b64 addrs across all 32 banks; lanes
    //      16..63 read identical addrs -> broadcast, conflict-free) ----
    const int row = b * ROWS + (t / TPR);
    const int c0  = t % TPR;
    const float px = pts[row].x;
    const float py = pts[row].y;

    // 4 accumulators to break the serial add chain (v_add dep latency ~4cyc)
    float a0 = 0.f, a1 = 0.f, a2 = 0.f, a3 = 0.f;
    #pragma unroll 2
    for (int k = c0; k < N_POINTS; k += 4 * TPR) {
        const float2 p0 = pts[k];
        const float2 p1 = pts[k + TPR];
        const float2 p2 = pts[k + 2 * TPR];
        const float2 p3 = pts[k + 3 * TPR];
        float dx, dy, d2;
        dx = px - p0.x; dy = py - p0.y;
        d2 = __builtin_fmaf(dx, dx, __builtin_fmaf(dy, dy, 1.0f));
        a0 += __builtin_amdgcn_rcpf(d2);
        dx = px - p1.x; dy = py - p1.y;
        d2 = __builtin_fmaf(dx, dx, __builtin_fmaf(dy, dy, 1.0f));
        a1 += __builtin_amdgcn_rcpf(d2);
        dx = px - p2.x; dy = py - p2.y;
        d2 = __builtin_fmaf(dx, dx, __builtin_fmaf(dy, dy, 1.0f));
        a2 += __builtin_amdgcn_rcpf(d2);
        dx = px - p3.x; dy = py - p3.y;
        d2 = __builtin_fmaf(dx, dx, __builtin_fmaf(dy, dy, 1.0f));
        a3 += __builtin_amdgcn_rcpf(d2);
    }
    float part = (a0 + a1) + (a2 + a3);

    // ---- phase 2: this block's 512-edge slice; points come from LDS ----
    float s1 = 0.f, sp = 0.f;
    #pragma unroll
    for (int it = 0; it < EPB / THREADS; ++it) {
        const int e = b * EPB + it * THREADS + t;    // coalesced index/pij loads
        const int ia = ei[e];
        const int ib = ej[e];
        const float2 pa = pts[ia];
        const float2 pb = pts[ib];
        const float dx = pa.x - pb.x;
        const float dy = pa.y - pb.y;
        const float d2 = __builtin_fmaf(dx, dx, __builtin_fmaf(dy, dy, 2.0f));
        const float p  = pij[e];
        s1 += p * (__logf(p) + __logf(d2));
        sp += p;
    }

    // ---- block reduction of (part, s1, sp) ----
    #pragma unroll
    for (int off = 32; off > 0; off >>= 1) {
        part += __shfl_down(part, off, 64);
        s1   += __shfl_down(s1,   off, 64);
        sp   += __shfl_down(sp,   off, 64);
    }
    const int w = t >> 6, l = t & 63;
    if (l == 0) { wred[0][w] = part; wred[1][w] = s1; wred[2][w] = sp; }
    __syncthreads();
    if (t == 0) {
        float r0 = 0.f, r1 = 0.f, r2 = 0.f;
        #pragma unroll
        for (int i = 0; i < THREADS / 64; ++i) {
            r0 += wred[0][i]; r1 += wred[1][i]; r2 += wred[2][i];
        }
        partials[0 * BLOCKS + b] = r0;
        partials[1 * BLOCKS + b] = r1;
        partials[2 * BLOCKS + b] = r2;
    }
}

// ---------------- Final reduce + combine (double precision) ----------------
__global__ __launch_bounds__(256)
void final_kernel(const float* __restrict__ partials, float* __restrict__ out) {
    __shared__ double ra[4], rs[4], rp[4];
    const int t = threadIdx.x;

    double a = (double)partials[0 * BLOCKS + t] + (double)partials[0 * BLOCKS + t + 256];
    double s = (double)partials[1 * BLOCKS + t] + (double)partials[1 * BLOCKS + t + 256];
    double p = (double)partials[2 * BLOCKS + t] + (double)partials[2 * BLOCKS + t + 256];

    #pragma unroll
    for (int off = 32; off > 0; off >>= 1) {
        a += __shfl_down(a, off, 64);
        s += __shfl_down(s, off, 64);
        p += __shfl_down(p, off, 64);
    }
    const int w = t >> 6, l = t & 63;
    if (l == 0) { ra[w] = a; rs[w] = s; rp[w] = p; }
    __syncthreads();
    if (t == 0) {
        double A = 0.0, S = 0.0, P = 0.0;
        #pragma unroll
        for (int i = 0; i < 4; ++i) { A += ra[i]; S += rs[i]; P += rp[i]; }
        A -= (double)N_POINTS;                 // remove diagonal (each term == 1)
        out[0] = (float)(S + log(A) * P);
    }
}

extern "C" void kernel_launch(void* const* d_in, const int* in_sizes, int n_in,
                              void* d_out, int out_size, void* d_ws, size_t ws_size,
                              hipStream_t stream) {
    const float* pij    = (const float*)d_in[0];
    const int*   ei     = (const int*)d_in[1];
    const int*   ej     = (const int*)d_in[2];
    const float* logits = (const float*)d_in[3];
    float* out = (float*)d_out;

    float* partials = (float*)d_ws;              // 3 * BLOCKS floats

    fused_kernel<<<BLOCKS, THREADS, 0, stream>>>(logits, pij, ei, ej, partials);
    final_kernel<<<1, 256, 0, stream>>>(partials, out);
}

// Round 3
// 80.519 us; speedup vs baseline: 1.0557x; 1.0120x over previous
//
#include <hip/hip_runtime.h>
#include <math.h>

#define N_POINTS 8192
#define N_PAIRS  262144

constexpr int BLOCKS  = 512;
constexpr int THREADS = 256;
constexpr int VROWS   = (N_POINTS / 2) / BLOCKS;   // 8 virtual rows per block
constexpr int TPV     = THREADS / VROWS;           // 32 threads per virtual row
constexpr int EPB     = N_PAIRS / BLOCKS;          // 512 edges per block

// ---------------- Fused kernel ----------------
// Virtual row g pairs real rows i=g and j=N-1-g; together they cover exactly
// N-1 upper-triangle columns, so every thread does ~(N-1)/TPV iterations.
// partials[0*B+b] = sum over block's vrows of sum_{k>i} 1/(1+||xi-xk||^2)  (S2 share)
// partials[1*B+b] = sum over block's edges of pij*(log pij + log(2+d2))
// partials[2*B+b] = sum over block's edges of pij
__global__ __launch_bounds__(THREADS)
void fused_kernel(const float* __restrict__ logits,
                  const float* __restrict__ pij,
                  const int* __restrict__ ei,
                  const int* __restrict__ ej,
                  float* __restrict__ partials) {
    __shared__ float2 pts[N_POINTS];             // 64 KiB -> 2 blocks/CU
    __shared__ float wred[3][THREADS / 64];

    const int t = threadIdx.x;
    const int b = blockIdx.x;

    // cooperative stage: 4096 float4, coalesced; src is 64 KB -> L2/L3 hot
    {
        const float4* src = (const float4*)logits;
        float4* dst = (float4*)pts;
        #pragma unroll
        for (int k = t; k < N_POINTS / 2; k += THREADS) dst[k] = src[k];
    }
    __syncthreads();

    // ---- phase 1: symmetric upper-triangle partition sum ----
    const int g  = b * VROWS + (t / TPV);        // virtual row
    const int c0 = t % TPV;
    const int i_row = g;
    const int j_row = N_POINTS - 1 - g;

    float acc1 = 0.0f, acc2 = 0.0f;

    {
        const float px = pts[i_row].x, py = pts[i_row].y;
        for (int k = i_row + 1 + c0; k < N_POINTS; k += TPV) {
            const float2 q = pts[k];
            const float dx = px - q.x;
            const float dy = py - q.y;
            const float d2 = __builtin_fmaf(dx, dx, __builtin_fmaf(dy, dy, 1.0f));
            acc1 += __builtin_amdgcn_rcpf(d2);
        }
    }
    {
        const float px = pts[j_row].x, py = pts[j_row].y;
        for (int k = j_row + 1 + c0; k < N_POINTS; k += TPV) {
            const float2 q = pts[k];
            const float dx = px - q.x;
            const float dy = py - q.y;
            const float d2 = __builtin_fmaf(dx, dx, __builtin_fmaf(dy, dy, 1.0f));
            acc2 += __builtin_amdgcn_rcpf(d2);
        }
    }
    float part = acc1 + acc2;                    // this thread's share of S2

    // ---- phase 2: this block's 512-edge slice; points from LDS ----
    float s1 = 0.0f, sp = 0.0f;
    #pragma unroll
    for (int it = 0; it < EPB / THREADS; ++it) {
        const int e = b * EPB + it * THREADS + t;    // coalesced index/pij loads
        const int ia = ei[e];
        const int ib = ej[e];
        const float2 pa = pts[ia];
        const float2 pb = pts[ib];
        const float dx = pa.x - pb.x;
        const float dy = pa.y - pb.y;
        const float d2 = __builtin_fmaf(dx, dx, __builtin_fmaf(dy, dy, 2.0f));
        const float p  = pij[e];
        s1 += p * (__logf(p) + __logf(d2));
        sp += p;
    }

    // ---- block reduction ----
    #pragma unroll
    for (int off = 32; off > 0; off >>= 1) {
        part += __shfl_down(part, off, 64);
        s1   += __shfl_down(s1,   off, 64);
        sp   += __shfl_down(sp,   off, 64);
    }
    const int w = t >> 6, l = t & 63;
    if (l == 0) { wred[0][w] = part; wred[1][w] = s1; wred[2][w] = sp; }
    __syncthreads();
    if (t == 0) {
        float r0 = 0.f, r1 = 0.f, r2 = 0.f;
        #pragma unroll
        for (int i = 0; i < THREADS / 64; ++i) {
            r0 += wred[0][i]; r1 += wred[1][i]; r2 += wred[2][i];
        }
        partials[0 * BLOCKS + b] = r0;
        partials[1 * BLOCKS + b] = r1;
        partials[2 * BLOCKS + b] = r2;
    }
}

// ---------------- Final reduce + combine (double precision) ----------------
__global__ __launch_bounds__(256)
void final_kernel(const float* __restrict__ partials, float* __restrict__ out) {
    __shared__ double ra[4], rs[4], rp[4];
    const int t = threadIdx.x;

    double a = (double)partials[0 * BLOCKS + t] + (double)partials[0 * BLOCKS + t + 256];
    double s = (double)partials[1 * BLOCKS + t] + (double)partials[1 * BLOCKS + t + 256];
    double p = (double)partials[2 * BLOCKS + t] + (double)partials[2 * BLOCKS + t + 256];

    #pragma unroll
    for (int off = 32; off > 0; off >>= 1) {
        a += __shfl_down(a, off, 64);
        s += __shfl_down(s, off, 64);
        p += __shfl_down(p, off, 64);
    }
    const int w = t >> 6, l = t & 63;
    if (l == 0) { ra[w] = a; rs[w] = s; rp[w] = p; }
    __syncthreads();
    if (t == 0) {
        double A = 0.0, S = 0.0, P = 0.0;
        #pragma unroll
        for (int i = 0; i < 4; ++i) { A += ra[i]; S += rs[i]; P += rp[i]; }
        A *= 2.0;                                // part_raw - N == 2 * S2
        out[0] = (float)(S + log(A) * P);
    }
}

extern "C" void kernel_launch(void* const* d_in, const int* in_sizes, int n_in,
                              void* d_out, int out_size, void* d_ws, size_t ws_size,
                              hipStream_t stream) {
    const float* pij    = (const float*)d_in[0];
    const int*   ei     = (const int*)d_in[1];
    const int*   ej     = (const int*)d_in[2];
    const float* logits = (const float*)d_in[3];
    float* out = (float*)d_out;

    float* partials = (float*)d_ws;              // 3 * BLOCKS floats

    fused_kernel<<<BLOCKS, THREADS, 0, stream>>>(logits, pij, ei, ej, partials);
    final_kernel<<<1, 256, 0, stream>>>(partials, out);
}

// Round 4
// 78.233 us; speedup vs baseline: 1.0865x; 1.0292x over previous
//
#include <hip/hip_runtime.h>
#include <math.h>

#define N_POINTS 8192
#define N_PAIRS  262144

constexpr int BLOCKS  = 512;
constexpr int THREADS = 256;
constexpr int RPB     = N_POINTS / BLOCKS;   // 16 rows per block
constexpr int RPT     = 4;                   // rows per thread (register-tiled)
constexpr int GROUPS  = RPB / RPT;           // 4 thread-groups per block
constexpr int TPG     = THREADS / GROUPS;    // 64 threads per group (one wave)
constexpr int EPB     = N_PAIRS / BLOCKS;    // 512 edges per block

// ---------------- Fused kernel ----------------
// Phase 1: full N^2 partition sum, register-tiled 4 rows/thread so one LDS
//          q-load feeds 4 independent FMA/rcp chains (ILP >= 8 after k-unroll).
// Phase 2: this block's 512-edge slice, points from LDS.
// partials[0*B+b] = sum over block's 16 rows of sum_k 1/(1+||xi-xk||^2)  (incl. diagonal)
// partials[1*B+b] = sum over block's edges of pij*(log pij + log(2+d2))
// partials[2*B+b] = sum over block's edges of pij
__global__ __launch_bounds__(THREADS)
void fused_kernel(const float* __restrict__ logits,
                  const float* __restrict__ pij,
                  const int* __restrict__ ei,
                  const int* __restrict__ ej,
                  float* __restrict__ partials) {
    __shared__ float2 pts[N_POINTS];             // 64 KiB -> 2 blocks/CU
    __shared__ float wred[3][THREADS / 64];

    const int t = threadIdx.x;
    const int b = blockIdx.x;

    // cooperative stage: 4096 float4, coalesced; src is 64 KB -> L2/L3 hot
    {
        const float4* src = (const float4*)logits;
        float4* dst = (float4*)pts;
        #pragma unroll
        for (int k = t; k < N_POINTS / 2; k += THREADS) dst[k] = src[k];
    }
    __syncthreads();

    // ---- phase 1: register-tiled partition sum ----
    const int g  = t / TPG;                      // group = wave (t>>6)
    const int c  = t % TPG;                      // lane
    const int r0 = b * RPB + g * RPT;

    const float2 p0 = pts[r0 + 0];
    const float2 p1 = pts[r0 + 1];
    const float2 p2 = pts[r0 + 2];
    const float2 p3 = pts[r0 + 3];

    float a0 = 0.f, a1 = 0.f, a2 = 0.f, a3 = 0.f;
    #pragma unroll 4
    for (int k = c; k < N_POINTS; k += TPG) {
        const float2 q = pts[k];                 // one LDS b64 feeds 4 rows
        float dx, dy, d2;
        dx = p0.x - q.x; dy = p0.y - q.y;
        d2 = __builtin_fmaf(dx, dx, __builtin_fmaf(dy, dy, 1.0f));
        a0 += __builtin_amdgcn_rcpf(d2);
        dx = p1.x - q.x; dy = p1.y - q.y;
        d2 = __builtin_fmaf(dx, dx, __builtin_fmaf(dy, dy, 1.0f));
        a1 += __builtin_amdgcn_rcpf(d2);
        dx = p2.x - q.x; dy = p2.y - q.y;
        d2 = __builtin_fmaf(dx, dx, __builtin_fmaf(dy, dy, 1.0f));
        a2 += __builtin_amdgcn_rcpf(d2);
        dx = p3.x - q.x; dy = p3.y - q.y;
        d2 = __builtin_fmaf(dx, dx, __builtin_fmaf(dy, dy, 1.0f));
        a3 += __builtin_amdgcn_rcpf(d2);
    }
    float part = (a0 + a1) + (a2 + a3);          // includes diagonal (==1/row)

    // ---- phase 2: this block's 512-edge slice; points from LDS ----
    float s1 = 0.0f, sp = 0.0f;
    #pragma unroll
    for (int it = 0; it < EPB / THREADS; ++it) {
        const int e = b * EPB + it * THREADS + t;    // coalesced index/pij loads
        const int ia = ei[e];
        const int ib = ej[e];
        const float2 pa = pts[ia];
        const float2 pb = pts[ib];
        const float dx = pa.x - pb.x;
        const float dy = pa.y - pb.y;
        const float d2 = __builtin_fmaf(dx, dx, __builtin_fmaf(dy, dy, 2.0f));
        const float p  = pij[e];
        s1 += p * (__logf(p) + __logf(d2));
        sp += p;
    }

    // ---- block reduction ----
    #pragma unroll
    for (int off = 32; off > 0; off >>= 1) {
        part += __shfl_down(part, off, 64);
        s1   += __shfl_down(s1,   off, 64);
        sp   += __shfl_down(sp,   off, 64);
    }
    const int w = t >> 6, l = t & 63;
    if (l == 0) { wred[0][w] = part; wred[1][w] = s1; wred[2][w] = sp; }
    __syncthreads();
    if (t == 0) {
        float r0s = 0.f, r1s = 0.f, r2s = 0.f;
        #pragma unroll
        for (int i = 0; i < THREADS / 64; ++i) {
            r0s += wred[0][i]; r1s += wred[1][i]; r2s += wred[2][i];
        }
        partials[0 * BLOCKS + b] = r0s;
        partials[1 * BLOCKS + b] = r1s;
        partials[2 * BLOCKS + b] = r2s;
    }
}

// ---------------- Final reduce + combine (double precision) ----------------
__global__ __launch_bounds__(256)
void final_kernel(const float* __restrict__ partials, float* __restrict__ out) {
    __shared__ double ra[4], rs[4], rp[4];
    const int t = threadIdx.x;

    double a = (double)partials[0 * BLOCKS + t] + (double)partials[0 * BLOCKS + t + 256];
    double s = (double)partials[1 * BLOCKS + t] + (double)partials[1 * BLOCKS + t + 256];
    double p = (double)partials[2 * BLOCKS + t] + (double)partials[2 * BLOCKS + t + 256];

    #pragma unroll
    for (int off = 32; off > 0; off >>= 1) {
        a += __shfl_down(a, off, 64);
        s += __shfl_down(s, off, 64);
        p += __shfl_down(p, off, 64);
    }
    const int w = t >> 6, l = t & 63;
    if (l == 0) { ra[w] = a; rs[w] = s; rp[w] = p; }
    __syncthreads();
    if (t == 0) {
        double A = 0.0, S = 0.0, P = 0.0;
        #pragma unroll
        for (int i = 0; i < 4; ++i) { A += ra[i]; S += rs[i]; P += rp[i]; }
        A -= (double)N_POINTS;                 // remove diagonal (each term == 1)
        out[0] = (float)(S + log(A) * P);
    }
}

extern "C" void kernel_launch(void* const* d_in, const int* in_sizes, int n_in,
                              void* d_out, int out_size, void* d_ws, size_t ws_size,
                              hipStream_t stream) {
    const float* pij    = (const float*)d_in[0];
    const int*   ei     = (const int*)d_in[1];
    const int*   ej     = (const int*)d_in[2];
    const float* logits = (const float*)d_in[3];
    float* out = (float*)d_out;

    float* partials = (float*)d_ws;              // 3 * BLOCKS floats

    fused_kernel<<<BLOCKS, THREADS, 0, stream>>>(logits, pij, ei, ej, partials);
    final_kernel<<<1, 256, 0, stream>>>(partials, out);
}

// Round 5
// 73.029 us; speedup vs baseline: 1.1639x; 1.0713x over previous
//
#include <hip/hip_runtime.h>
#include <math.h>

#define N_POINTS 8192
#define N_PAIRS  262144

constexpr int BLOCKS  = 512;
constexpr int THREADS = 256;
constexpr int TILE    = 8;                    // rows per virtual tile
constexpr int NTILES  = N_POINTS / TILE;      // 1024 tiles; block b does tiles {b, 1023-b}
constexpr int EPB     = N_PAIRS / BLOCKS;     // 512 edges per block

// ---------------- Fused kernel ----------------
// Phase 1 (symmetric triangle, register-tiled): tile v = rows [8v,8v+8) sweeps
// columns k in [8v, N). One LDS q-load feeds 8 independent FMA/rcp chains.
// S_all = 2*T - sum_v D_v  (D_v = tile v's 8x8 diagonal square, incl. i==k).
// Block b handles tiles b and 1023-b -> exactly 8200 swept columns per block,
// uniform work under any block->CU mapping.
// partials[0*B+b] = block share of S_all (incl. diagonal, subtracted later)
// partials[1*B+b] = sum over block's edges of pij*(log pij + log(2+d2))
// partials[2*B+b] = sum over block's edges of pij
__global__ __launch_bounds__(THREADS)
void fused_kernel(const float* __restrict__ logits,
                  const float* __restrict__ pij,
                  const int* __restrict__ ei,
                  const int* __restrict__ ej,
                  float* __restrict__ partials) {
    __shared__ float2 pts[N_POINTS];             // 64 KiB -> 2 blocks/CU
    __shared__ float wred[3][THREADS / 64];

    const int t = threadIdx.x;
    const int b = blockIdx.x;

    // cooperative stage: 4096 float4, coalesced; src is 64 KB -> L2/L3 hot
    {
        const float4* src = (const float4*)logits;
        float4* dst = (float4*)pts;
        #pragma unroll
        for (int k = t; k < N_POINTS / 2; k += THREADS) dst[k] = src[k];
    }
    __syncthreads();

    const int v1 = b;
    const int v2 = NTILES - 1 - b;

    // ---- phase 1: wedge sweep for one tile (8 rows in registers) ----
    auto sweep = [&](int v) -> float {
        const int r0 = v * TILE;
        float rx[TILE], ry[TILE];
        #pragma unroll
        for (int r = 0; r < TILE; ++r) { rx[r] = pts[r0 + r].x; ry[r] = pts[r0 + r].y; }
        float a[TILE];
        #pragma unroll
        for (int r = 0; r < TILE; ++r) a[r] = 0.0f;
        #pragma unroll 2
        for (int k = r0 + t; k < N_POINTS; k += THREADS) {
            const float2 q = pts[k];             // one LDS b64 feeds 8 rows
            #pragma unroll
            for (int r = 0; r < TILE; ++r) {
                const float dx = rx[r] - q.x;
                const float dy = ry[r] - q.y;
                const float d2 = __builtin_fmaf(dx, dx, __builtin_fmaf(dy, dy, 1.0f));
                a[r] += __builtin_amdgcn_rcpf(d2);
            }
        }
        float s = 0.0f;
        #pragma unroll
        for (int r = 0; r < TILE; ++r) s += a[r];
        return s;
    };

    float T = sweep(v1) + sweep(v2);

    // diagonal 8x8 squares: 64 pairs per tile, one per lane (waves 0 and 1)
    float Dc = 0.0f;
    if (t < 128) {
        const int v = (t < 64) ? v1 : v2;
        const int l = t & 63;
        const int i = v * TILE + (l >> 3);
        const int k = v * TILE + (l & 7);
        const float dx = pts[i].x - pts[k].x;
        const float dy = pts[i].y - pts[k].y;
        const float d2 = __builtin_fmaf(dx, dx, __builtin_fmaf(dy, dy, 1.0f));
        Dc = __builtin_amdgcn_rcpf(d2);
    }
    float part = __builtin_fmaf(2.0f, T, -Dc);   // block-sum -> share of S_all

    // ---- phase 2: this block's 512-edge slice; vectorized 8B loads ----
    float s1 = 0.0f, sp = 0.0f;
    {
        const int2   ea = ((const int2*)(ei + b * EPB))[t];
        const int2   eb = ((const int2*)(ej + b * EPB))[t];
        const float2 pp = ((const float2*)(pij + b * EPB))[t];

        float2 pa = pts[ea.x], pb = pts[eb.x];
        float dx = pa.x - pb.x, dy = pa.y - pb.y;
        float d2 = __builtin_fmaf(dx, dx, __builtin_fmaf(dy, dy, 2.0f));
        s1 += pp.x * (__logf(pp.x) + __logf(d2));
        sp += pp.x;

        pa = pts[ea.y]; pb = pts[eb.y];
        dx = pa.x - pb.x; dy = pa.y - pb.y;
        d2 = __builtin_fmaf(dx, dx, __builtin_fmaf(dy, dy, 2.0f));
        s1 += pp.y * (__logf(pp.y) + __logf(d2));
        sp += pp.y;
    }

    // ---- block reduction ----
    #pragma unroll
    for (int off = 32; off > 0; off >>= 1) {
        part += __shfl_down(part, off, 64);
        s1   += __shfl_down(s1,   off, 64);
        sp   += __shfl_down(sp,   off, 64);
    }
    const int w = t >> 6, l = t & 63;
    if (l == 0) { wred[0][w] = part; wred[1][w] = s1; wred[2][w] = sp; }
    __syncthreads();
    if (t == 0) {
        float r0s = 0.f, r1s = 0.f, r2s = 0.f;
        #pragma unroll
        for (int i = 0; i < THREADS / 64; ++i) {
            r0s += wred[0][i]; r1s += wred[1][i]; r2s += wred[2][i];
        }
        partials[0 * BLOCKS + b] = r0s;
        partials[1 * BLOCKS + b] = r1s;
        partials[2 * BLOCKS + b] = r2s;
    }
}

// ---------------- Final reduce + combine (double precision) ----------------
__global__ __launch_bounds__(256)
void final_kernel(const float* __restrict__ partials, float* __restrict__ out) {
    __shared__ double ra[4], rs[4], rp[4];
    const int t = threadIdx.x;

    double a = (double)partials[0 * BLOCKS + t] + (double)partials[0 * BLOCKS + t + 256];
    double s = (double)partials[1 * BLOCKS + t] + (double)partials[1 * BLOCKS + t + 256];
    double p = (double)partials[2 * BLOCKS + t] + (double)partials[2 * BLOCKS + t + 256];

    #pragma unroll
    for (int off = 32; off > 0; off >>= 1) {
        a += __shfl_down(a, off, 64);
        s += __shfl_down(s, off, 64);
        p += __shfl_down(p, off, 64);
    }
    const int w = t >> 6, l = t & 63;
    if (l == 0) { ra[w] = a; rs[w] = s; rp[w] = p; }
    __syncthreads();
    if (t == 0) {
        double A = 0.0, S = 0.0, P = 0.0;
        #pragma unroll
        for (int i = 0; i < 4; ++i) { A += ra[i]; S += rs[i]; P += rp[i]; }
        A -= (double)N_POINTS;                 // remove diagonal (each term == 1)
        out[0] = (float)(S + log(A) * P);
    }
}

extern "C" void kernel_launch(void* const* d_in, const int* in_sizes, int n_in,
                              void* d_out, int out_size, void* d_ws, size_t ws_size,
                              hipStream_t stream) {
    const float* pij    = (const float*)d_in[0];
    const int*   ei     = (const int*)d_in[1];
    const int*   ej     = (const int*)d_in[2];
    const float* logits = (const float*)d_in[3];
    float* out = (float*)d_out;

    float* partials = (float*)d_ws;              // 3 * BLOCKS floats

    fused_kernel<<<BLOCKS, THREADS, 0, stream>>>(logits, pij, ei, ej, partials);
    final_kernel<<<1, 256, 0, stream>>>(partials, out);
}